// Round 1
// baseline (218.638 us; speedup 1.0000x reference)
//
#include <hip/hip_runtime.h>
#include <stdint.h>

// IndexedLinearLayer as implicit-A GEMM — R10: single-node fused kernel.
//
// Evidence (R9 rocprof): top-5 dispatches are all 256 MiB ws-poison fills
// (~43.5 µs each, 2/iter = 87 µs, 77% HBM peak); measured total 90.0 µs.
// Kernel work is hidden under the fills; the residual ~3 µs is node
// overhead + our own ws traffic (8 MB write + 8 MB read).
//
// R10: out = sum_q maskedGEMM_q needs NO split-K reduction — accumulate
// across q in the MFMA accumulators inside one block. One kernel, one
// graph node, zero workspace traffic, no memset/atomics.
//   grid = 16 bt x 4 nh = 64 blocks, TM=32, TN=64, 256 thr (4 waves,
//   each wave owns 16 out cols). Per q: restage masked bf16 A-tile
//   (x/idx L2-resident), run 16x16x32 MFMA K-loop, acc carries over q.
// Predicted: dur 90.0 -> ~86.5 (fill floor). If >=89.5: harness roofline.

constexpr int SIZE_IN  = 1024;
constexpr int SIZE_OUT = 256;
constexpr int BATCH    = 512;
constexpr int NUM_Q    = 16;
constexpr int TM = 32;             // batch tile
constexpr int TN = 64;             // out tile (4 nh slices)
constexpr int A_STRIDE = 1032;     // bf16 elems/row, +8 pad

typedef short short8   __attribute__((ext_vector_type(8)));
typedef float floatx4  __attribute__((ext_vector_type(4)));

__device__ inline uint32_t pack2bf(float lo, float hi) {
    uint32_t a = __float_as_uint(lo) + 0x8000u;
    uint32_t b = __float_as_uint(hi) + 0x8000u;
    return __builtin_amdgcn_perm(b, a, 0x07060302);  // {b.hi16, a.hi16}
}

__global__ __launch_bounds__(256, 2)
void idxlin_fused(const float* __restrict__ x,      // [512,1024]
                  const int*   __restrict__ idx,    // [512,1024]
                  const float* __restrict__ table,  // [16*1024, 256]
                  const float* __restrict__ bias,   // [256]
                  float*       __restrict__ out)    // [512,256]
{
    __shared__ uint16_t Alds[TM * A_STRIDE];        // 66 KB

    const int tid = threadIdx.x;
    const int nh  = blockIdx.x & 3;
    const int bt  = blockIdx.x >> 2;
    const int b0  = bt * TM;
    const int n0  = nh * TN;

    const int lane  = tid & 63;
    const int w     = tid >> 6;        // wave: owns out cols [n0+w*16, +16)
    const int nlane = lane & 15;
    const int quad  = lane >> 4;

    const float4* x4 = reinterpret_cast<const float4*>(x   + b0 * SIZE_IN);
    const int4*   i4 = reinterpret_cast<const int4*>(idx + b0 * SIZE_IN);

    const uint16_t* arow0 = &Alds[(0 * 16 + nlane) * A_STRIDE + quad * 8];
    const uint16_t* arow1 = &Alds[(1 * 16 + nlane) * A_STRIDE + quad * 8];

    floatx4 acc[2] = {{0.f,0.f,0.f,0.f},{0.f,0.f,0.f,0.f}};

    for (int q = 0; q < NUM_Q; ++q) {
        // ---- Stage masked-x A-tile into LDS (bf16). Iter s fills row s. ----
        __syncthreads();               // prev q's MFMA reads done before overwrite
        #pragma unroll 4
        for (int s = 0; s < TM; ++s) {
            const int f = s * 256 + tid;
            const float4 xv = x4[f];
            const int4   iv = i4[f];
            const float v0 = (iv.x == q) ? xv.x : 0.f;
            const float v1 = (iv.y == q) ? xv.y : 0.f;
            const float v2 = (iv.z == q) ? xv.z : 0.f;
            const float v3 = (iv.w == q) ? xv.w : 0.f;
            uint2 d;
            d.x = pack2bf(v0, v1);
            d.y = pack2bf(v2, v3);
            *reinterpret_cast<uint2*>(&Alds[s * A_STRIDE + tid * 4]) = d;
        }
        __syncthreads();

        // ---- MFMA K-loop, accumulating across q ----
        const float* bp = table + (q * SIZE_IN + quad * 8) * SIZE_OUT
                        + n0 + w * 16 + nlane;
        #pragma unroll 2
        for (int kb = 0; kb < SIZE_IN / 32; ++kb) {
            float wv[8];
            #pragma unroll
            for (int j = 0; j < 8; ++j)
                wv[j] = bp[j * SIZE_OUT];

            const short8 a0 = *reinterpret_cast<const short8*>(arow0 + kb * 32);
            const short8 a1 = *reinterpret_cast<const short8*>(arow1 + kb * 32);

            union { uint32_t u[4]; short8 s; } bf;
            bf.u[0] = pack2bf(wv[0], wv[1]);
            bf.u[1] = pack2bf(wv[2], wv[3]);
            bf.u[2] = pack2bf(wv[4], wv[5]);
            bf.u[3] = pack2bf(wv[6], wv[7]);
            acc[0] = __builtin_amdgcn_mfma_f32_16x16x32_bf16(a0, bf.s, acc[0], 0, 0, 0);
            acc[1] = __builtin_amdgcn_mfma_f32_16x16x32_bf16(a1, bf.s, acc[1], 0, 0, 0);
            bp += 32 * SIZE_OUT;
        }
    }

    // ---- Direct output write + bias. C/D layout: col=lane&15, row=quad*4+reg ----
    const int col = n0 + w * 16 + nlane;
    const float bv = bias[col];
    #pragma unroll
    for (int mt = 0; mt < 2; ++mt)
        #pragma unroll
        for (int rr = 0; rr < 4; ++rr) {
            const int row = b0 + mt * 16 + quad * 4 + rr;
            out[row * SIZE_OUT + col] = acc[mt][rr] + bv;
        }
}

extern "C" void kernel_launch(void* const* d_in, const int* in_sizes, int n_in,
                              void* d_out, int out_size, void* d_ws, size_t ws_size,
                              hipStream_t stream) {
    const float* x     = (const float*)d_in[0];
    const int*   idx   = (const int*)d_in[1];
    const float* table = (const float*)d_in[2];
    const float* bias  = (const float*)d_in[3];
    float*       out   = (float*)d_out;
    (void)d_ws; (void)ws_size;

    idxlin_fused<<<dim3((BATCH / TM) * (SIZE_OUT / TN)), dim3(256), 0, stream>>>(
        x, idx, table, bias, out);
}

// Round 2
// 150.840 us; speedup vs baseline: 1.4495x; 1.4495x over previous
//
#include <hip/hip_runtime.h>
#include <stdint.h>

// IndexedLinearLayer — R11: single-node, q-split-across-waves.
//
// R10 post-mortem: 1-node fused kernel at 64 blocks ran 212 µs (Occupancy
// 2.9%, MfmaUtil 0.9%, HBM 1.5%) — latency-bound, 1 wave/SIMD on 25% of
// CUs, 4096 dependent scalar table loads/thread unhidden. dur = max(fill
// shadow ~87 µs, kernel) + eps, so the kernel must simply be << 87 µs.
//
// R11: out tile accumulates over BOTH k and q in one register acc, so q
// splits across waves with an end LDS reduce (still one node, no ws, no
// atomics, no memset):
//   grid = 32 bt x 16 nh = 512 blocks, 512 thr = 8 waves (4 waves/SIMD
//   chip-wide). Each wave: 16x16 out tile, q in {2w, 2w+1}, K-loop with
//   in-register masking of x by (idx==q) — no per-q LDS restage.
//   Fragment mappings identical to the harness-verified R3/R10 kernels.
//   nh = low 4 bits of blockIdx -> each XCD sees 2 table col-slices (2 MB).
// Predicted: kernel ~20-35 µs under the ~87 µs poison-fill shadow; dur
// 218.6 -> ~86-90. If >= 89.5: harness fill floor, stop.

constexpr int SIZE_IN  = 1024;
constexpr int SIZE_OUT = 256;
constexpr int BATCH    = 512;
constexpr int NUM_Q    = 16;

typedef short short8   __attribute__((ext_vector_type(8)));
typedef float floatx4  __attribute__((ext_vector_type(4)));

__device__ inline uint32_t pack2bf(float lo, float hi) {
    uint32_t a = __float_as_uint(lo) + 0x8000u;
    uint32_t b = __float_as_uint(hi) + 0x8000u;
    return __builtin_amdgcn_perm(b, a, 0x07060302);  // {b.hi16, a.hi16}
}

__global__ __launch_bounds__(512, 4)
void idxlin_qsplit(const float* __restrict__ x,      // [512,1024]
                   const int*   __restrict__ idx,    // [512,1024] (int32 in harness)
                   const float* __restrict__ table,  // [16*1024, 256]
                   const float* __restrict__ bias,   // [256]
                   float*       __restrict__ out)    // [512,256]
{
    __shared__ float red[8][64][4];                  // 8 KB wave-reduce buffer

    const int tid   = threadIdx.x;
    const int lane  = tid & 63;
    const int w     = tid >> 6;          // wave 0..7 -> q in {2w, 2w+1}
    const int nlane = lane & 15;
    const int quad  = lane >> 4;

    const int nh = blockIdx.x & 15;      // XCD = blk%8 = nh%8 -> 2 col-slices/XCD
    const int bt = blockIdx.x >> 4;
    const int b0 = bt * 16;
    const int n0 = nh * 16;

    // A-frag source: x[b0+nlane][kb*32 + quad*8 .. +8] (proven mapping)
    const float* xp = x   + (b0 + nlane) * SIZE_IN + quad * 8;
    const int*   ip = idx + (b0 + nlane) * SIZE_IN + quad * 8;
    const int q0 = w * 2;

    floatx4 acc = {0.f, 0.f, 0.f, 0.f};

    #pragma unroll 2
    for (int kb = 0; kb < SIZE_IN / 32; ++kb) {
        const float4 xv0 = *reinterpret_cast<const float4*>(xp + kb * 32);
        const float4 xv1 = *reinterpret_cast<const float4*>(xp + kb * 32 + 4);
        const int4   iv0 = *reinterpret_cast<const int4*>(ip + kb * 32);
        const int4   iv1 = *reinterpret_cast<const int4*>(ip + kb * 32 + 4);

        #pragma unroll
        for (int qq = 0; qq < 2; ++qq) {
            const int q = q0 + qq;

            union { uint32_t u[4]; short8 s; } af;   // masked A frag (bf16)
            af.u[0] = pack2bf(iv0.x == q ? xv0.x : 0.f, iv0.y == q ? xv0.y : 0.f);
            af.u[1] = pack2bf(iv0.z == q ? xv0.z : 0.f, iv0.w == q ? xv0.w : 0.f);
            af.u[2] = pack2bf(iv1.x == q ? xv1.x : 0.f, iv1.y == q ? xv1.y : 0.f);
            af.u[3] = pack2bf(iv1.z == q ? xv1.z : 0.f, iv1.w == q ? xv1.w : 0.f);

            // B-frag: col = n0+nlane, k rows q*1024 + kb*32 + quad*8 + j
            const float* bp = table
                + ((q * SIZE_IN + kb * 32 + quad * 8) * SIZE_OUT) + n0 + nlane;
            float wv[8];
            #pragma unroll
            for (int j = 0; j < 8; ++j) wv[j] = bp[j * SIZE_OUT];

            union { uint32_t u[4]; short8 s; } bf;
            bf.u[0] = pack2bf(wv[0], wv[1]);
            bf.u[1] = pack2bf(wv[2], wv[3]);
            bf.u[2] = pack2bf(wv[4], wv[5]);
            bf.u[3] = pack2bf(wv[6], wv[7]);

            acc = __builtin_amdgcn_mfma_f32_16x16x32_bf16(af.s, bf.s, acc, 0, 0, 0);
        }
    }

    // ---- reduce 8 waves' accs in LDS, add bias, write ----
    #pragma unroll
    for (int rr = 0; rr < 4; ++rr) red[w][lane][rr] = acc[rr];
    __syncthreads();

    if (tid < 256) {
        const int l  = tid >> 2;         // lane id 0..63
        const int rr = tid & 3;          // acc reg
        float s = red[0][l][rr];
        #pragma unroll
        for (int ww = 1; ww < 8; ++ww) s += red[ww][l][rr];
        const int row = b0 + (l >> 4) * 4 + rr;   // C/D: row = quad*4 + reg
        const int col = n0 + (l & 15);            //      col = nlane
        out[row * SIZE_OUT + col] = s + bias[col];
    }
}

extern "C" void kernel_launch(void* const* d_in, const int* in_sizes, int n_in,
                              void* d_out, int out_size, void* d_ws, size_t ws_size,
                              hipStream_t stream) {
    const float* x     = (const float*)d_in[0];
    const int*   idx   = (const int*)d_in[1];
    const float* table = (const float*)d_in[2];
    const float* bias  = (const float*)d_in[3];
    float*       out   = (float*)d_out;
    (void)d_ws; (void)ws_size;

    idxlin_qsplit<<<dim3((BATCH / 16) * (SIZE_OUT / 16)), dim3(512), 0, stream>>>(
        x, idx, table, bias, out);
}

// Round 3
// 110.479 us; speedup vs baseline: 1.9790x; 1.3653x over previous
//
#include <hip/hip_runtime.h>
#include <stdint.h>

// IndexedLinearLayer — R12: single-node, q-split + LDS-staged x/idx.
//
// R11 post-mortem: 93-101 µs kernel, all pipes <20% — transaction-bound:
// scattered per-wave x/idx fragment loads (~24-32 lines/inst, 8x redundant
// across waves) + 16 scalar table loads/kb. ~45 M cache-line transactions.
//
// R12 keeps R11's parallelism (512 blocks x 8 waves, QW=2 q-split,
// register q-accum, LDS reduce, ONE graph node, no ws) and:
//  - stages x as bf16 + idx as 4-bit nibbles into LDS once per block
//    (coalesced float4/int4), A-frags via ds_read_b128 + 4B nibble word,
//    per-q masking in-register (cmp/cndmask on packed bf16 halves)
//  - XOR-swizzled LDS (rows at 2048 B / 512 B stride would be 16-way
//    bank-conflicted; ^((row&7)<<4) resp ^((row&15)<<2) fixes)
//  - XCD-exact mapping: blk = bt*16 + half*8 + h, nh = 2h+half ->
//    both 64-B col-halves of each 128-B table line on XCD h; per-XCD L2
//    holds its 2 MB table col-slice (32x in-L2 reuse).
// Predicted: kernel ~15-25 µs standalone, total 150.8 -> ~87-92 (fill
// floor: two unconditional 256-MiB ws-poison fills ~87 µs).

constexpr int SIZE_IN  = 1024;
constexpr int SIZE_OUT = 256;
constexpr int BATCH    = 512;
constexpr int NUM_Q    = 16;
constexpr int TM = 16;             // batch rows per block
constexpr int TN = 16;             // out cols per block

typedef short short8   __attribute__((ext_vector_type(8)));
typedef float floatx4  __attribute__((ext_vector_type(4)));

__device__ inline uint32_t pack2bf(float lo, float hi) {
    uint32_t a = __float_as_uint(lo) + 0x8000u;
    uint32_t b = __float_as_uint(hi) + 0x8000u;
    return __builtin_amdgcn_perm(b, a, 0x07060302);  // {hi.bf16 : lo.bf16}
}

__global__ __launch_bounds__(512, 4)
void idxlin_qsplit2(const float* __restrict__ x,      // [512,1024]
                    const int*   __restrict__ idx,    // [512,1024]
                    const float* __restrict__ table,  // [16*1024, 256]
                    const float* __restrict__ bias,   // [256]
                    float*       __restrict__ out)    // [512,256]
{
    __shared__ uint16_t x_lds[TM * 1024];   // bf16, row stride 2048 B, swizzled
    __shared__ uint32_t i_lds[TM * 128];    // 4-bit nibbles, row stride 512 B, swizzled
    __shared__ float    red[8][64][4];      // wave-reduce buffer (8 KB)

    const int tid = threadIdx.x;            // 0..511

    // XCD-exact decode: blk = bt*16 + half*8 + h ; nh = 2h + half
    const int h    = blockIdx.x & 7;
    const int half = (blockIdx.x >> 3) & 1;
    const int bt   = blockIdx.x >> 4;
    const int nh   = h * 2 + half;
    const int b0   = bt * TM;
    const int n0   = nh * TN;

    // ---- Stage x -> bf16 LDS (coalesced float4) ----
    const float4* x4 = reinterpret_cast<const float4*>(x + b0 * SIZE_IN);
    char* xb = reinterpret_cast<char*>(x_lds);
    #pragma unroll
    for (int it = 0; it < 8; ++it) {
        const int u   = it * 512 + tid;     // f4-unit 0..4095
        const int row = u >> 8;             // 256 f4 per row
        const int c8  = u & 255;
        const float4 xv = x4[u];
        uint2 d;
        d.x = pack2bf(xv.x, xv.y);
        d.y = pack2bf(xv.z, xv.w);
        const int byte = row * 2048 + ((c8 * 8) ^ ((row & 7) << 4));
        *reinterpret_cast<uint2*>(xb + byte) = d;
    }

    // ---- Stage idx -> packed nibbles in LDS (coalesced int4 pairs) ----
    const int4* i4 = reinterpret_cast<const int4*>(idx + b0 * SIZE_IN);
    char* ib = reinterpret_cast<char*>(i_lds);
    #pragma unroll
    for (int it = 0; it < 4; ++it) {
        const int u   = it * 512 + tid;     // u32-unit 0..2047 (8 idx each)
        const int row = u >> 7;             // 128 units per row
        const int c32 = u & 127;
        const int4 a = i4[2 * u];
        const int4 b = i4[2 * u + 1];
        const uint32_t n =  (uint32_t)a.x        | ((uint32_t)a.y << 4)
                         | ((uint32_t)a.z << 8)  | ((uint32_t)a.w << 12)
                         | ((uint32_t)b.x << 16) | ((uint32_t)b.y << 20)
                         | ((uint32_t)b.z << 24) | ((uint32_t)b.w << 28);
        const int byte = row * 512 + ((c32 * 4) ^ ((row & 15) << 2));
        *reinterpret_cast<uint32_t*>(ib + byte) = n;
    }
    __syncthreads();

    // ---- MFMA K-loop: q in {2w, 2w+1}, accumulate both into one acc ----
    const int lane  = tid & 63;
    const int w     = tid >> 6;
    const int nlane = lane & 15;
    const int quad  = lane >> 4;
    const int q0    = w * 2;

    const char* xrow = xb + nlane * 2048;
    const char* irow = ib + nlane * 512;
    const int   sx   = (nlane & 7) << 4;
    const int   si   = (nlane & 15) << 2;

    const float* bq0 = table + ((q0 * SIZE_IN + quad * 8) * SIZE_OUT) + n0 + nlane;
    const float* bq1 = bq0 + SIZE_IN * SIZE_OUT;

    floatx4 acc = {0.f, 0.f, 0.f, 0.f};

    #pragma unroll 2
    for (int kb = 0; kb < SIZE_IN / 32; ++kb) {
        union { uint32_t u[4]; short8 s; } ar;
        ar.s = *reinterpret_cast<const short8*>(xrow + ((kb * 64 + quad * 16) ^ sx));
        const uint32_t nib = *reinterpret_cast<const uint32_t*>(
                                 irow + ((kb * 16 + quad * 4) ^ si));
        uint32_t en[8];
        #pragma unroll
        for (int j = 0; j < 8; ++j) en[j] = (nib >> (4 * j)) & 15u;

        #pragma unroll
        for (int qq = 0; qq < 2; ++qq) {
            const uint32_t q = (uint32_t)(q0 + qq);
            const float* bp = qq ? bq1 : bq0;

            float wv[8];
            #pragma unroll
            for (int j = 0; j < 8; ++j) wv[j] = bp[j * SIZE_OUT];

            union { uint32_t u[4]; short8 s; } af;
            #pragma unroll
            for (int p = 0; p < 4; ++p) {
                const uint32_t msk = (en[2*p]     == q ? 0x0000FFFFu : 0u)
                                   | (en[2*p + 1] == q ? 0xFFFF0000u : 0u);
                af.u[p] = ar.u[p] & msk;
            }

            union { uint32_t u[4]; short8 s; } bf;
            bf.u[0] = pack2bf(wv[0], wv[1]);
            bf.u[1] = pack2bf(wv[2], wv[3]);
            bf.u[2] = pack2bf(wv[4], wv[5]);
            bf.u[3] = pack2bf(wv[6], wv[7]);

            acc = __builtin_amdgcn_mfma_f32_16x16x32_bf16(af.s, bf.s, acc, 0, 0, 0);
        }
        bq0 += 32 * SIZE_OUT;
        bq1 += 32 * SIZE_OUT;
    }

    // ---- reduce 8 waves' accs in LDS, add bias, write ----
    #pragma unroll
    for (int rr = 0; rr < 4; ++rr) red[w][lane][rr] = acc[rr];
    __syncthreads();

    if (tid < 256) {
        const int l  = tid >> 2;         // lane id 0..63
        const int rr = tid & 3;          // acc reg
        float s = red[0][l][rr];
        #pragma unroll
        for (int ww = 1; ww < 8; ++ww) s += red[ww][l][rr];
        const int row = b0 + (l >> 4) * 4 + rr;   // C/D: row = quad*4 + reg
        const int col = n0 + (l & 15);            //      col = nlane
        out[row * SIZE_OUT + col] = s + bias[col];
    }
}

extern "C" void kernel_launch(void* const* d_in, const int* in_sizes, int n_in,
                              void* d_out, int out_size, void* d_ws, size_t ws_size,
                              hipStream_t stream) {
    const float* x     = (const float*)d_in[0];
    const int*   idx   = (const int*)d_in[1];
    const float* table = (const float*)d_in[2];
    const float* bias  = (const float*)d_in[3];
    float*       out   = (float*)d_out;
    (void)d_ws; (void)ws_size;

    idxlin_qsplit2<<<dim3((BATCH / TM) * (SIZE_OUT / TN)), dim3(512), 0, stream>>>(
        x, idx, table, bias, out);
}